// Round 1
// baseline (737.019 us; speedup 1.0000x reference)
//
#include <hip/hip_runtime.h>
#include <hip/hip_bf16.h>

#define NCTX 4080
#define TPAD 4096
#define NS   1024
#define NH   16
#define DH   64

typedef __attribute__((ext_vector_type(8))) short short8;
typedef __attribute__((ext_vector_type(4))) float f32x4;
typedef unsigned short u16;
typedef unsigned int   u32;

#define MFMA(a,b,c) __builtin_amdgcn_mfma_f32_16x16x32_bf16(a,b,c,0,0,0)

__device__ __forceinline__ u16 f2bf(float f) {
  u32 u = __float_as_uint(f);
  u += 0x7fffu + ((u >> 16) & 1u);   // RNE; inputs are finite
  return (u16)(u >> 16);
}

__device__ __forceinline__ void gload16(const void* g, void* l) {
  __builtin_amdgcn_global_load_lds(
      (const __attribute__((address_space(1))) u32*)g,
      (__attribute__((address_space(3))) u32*)l, 16, 0, 0);
}

// ---------------- LayerNorm -> bf16 r (zero-padded to 4096 rows) -------------
__global__ __launch_bounds__(256) void ln_kernel(const float* __restrict__ mm,
    const float* __restrict__ gamma, const float* __restrict__ beta,
    u16* __restrict__ r) {
  int row = blockIdx.x;
  int t = threadIdx.x;
  if (row >= NCTX) {
    ushort4 z; z.x = z.y = z.z = z.w = 0;
    *reinterpret_cast<ushort4*>(&r[(size_t)row*NS + t*4]) = z;
    return;
  }
  float4 x = *reinterpret_cast<const float4*>(&mm[(size_t)row*NS + t*4]);
  float s  = x.x + x.y + x.z + x.w;
  float ss = x.x*x.x + x.y*x.y + x.z*x.z + x.w*x.w;
  for (int off = 32; off > 0; off >>= 1) {
    s  += __shfl_down(s, off);
    ss += __shfl_down(ss, off);
  }
  __shared__ float red[2][4];
  int wid = t >> 6, lane = t & 63;
  if (lane == 0) { red[0][wid] = s; red[1][wid] = ss; }
  __syncthreads();
  s  = red[0][0] + red[0][1] + red[0][2] + red[0][3];
  ss = red[1][0] + red[1][1] + red[1][2] + red[1][3];
  float mu  = s * (1.f/NS);
  float var = ss * (1.f/NS) - mu*mu;
  float rs  = rsqrtf(var + 1e-5f);
  float4 g = *reinterpret_cast<const float4*>(&gamma[t*4]);
  float4 b = *reinterpret_cast<const float4*>(&beta[t*4]);
  ushort4 o;
  o.x = f2bf((x.x - mu)*rs*g.x + b.x);
  o.y = f2bf((x.y - mu)*rs*g.y + b.y);
  o.z = f2bf((x.z - mu)*rs*g.z + b.z);
  o.w = f2bf((x.w - mu)*rs*g.w + b.w);
  *reinterpret_cast<ushort4*>(&r[(size_t)row*NS + t*4]) = o;
}

// ------------- Weight convert: W (KxN f32) -> W^T (NxK bf16) ----------------
__global__ __launch_bounds__(256) void wconv_kernel(const float* __restrict__ W0,
    const float* __restrict__ W1, const float* __restrict__ W2,
    const float* __restrict__ W3, u16* __restrict__ dstbase) {
  const float* srcs[4] = {W0, W1, W2, W3};
  const float* W = srcs[blockIdx.z];
  u16* dst = dstbase + (size_t)blockIdx.z * NS * NS;
  int k0 = blockIdx.x * 64, n0 = blockIdx.y * 64;
  __shared__ float tile[64][65];
  int t = threadIdx.x;
  int rr = t >> 4;
  int c4 = (t & 15) * 4;
  #pragma unroll
  for (int sb = 0; sb < 4; sb++) {
    int rowk = rr + sb*16;
    float4 v = *reinterpret_cast<const float4*>(&W[(size_t)(k0+rowk)*NS + n0 + c4]);
    tile[rowk][c4] = v.x; tile[rowk][c4+1] = v.y;
    tile[rowk][c4+2] = v.z; tile[rowk][c4+3] = v.w;
  }
  __syncthreads();
  #pragma unroll
  for (int sb = 0; sb < 4; sb++) {
    int nn = rr + sb*16;
    ushort4 o;
    o.x = f2bf(tile[c4  ][nn]);
    o.y = f2bf(tile[c4+1][nn]);
    o.z = f2bf(tile[c4+2][nn]);
    o.w = f2bf(tile[c4+3][nn]);
    *reinterpret_cast<ushort4*>(&dst[(size_t)(n0+nn)*NS + k0 + c4]) = o;
  }
}

// --------- QKV projection GEMM: C = r @ W (+bias) (tile 128x128, BK=32) -----
// z=0: q (scale 1/8, bias bq, row-major)  z=1: k (no bias)  z=2: v (bias bv, transposed out)
__global__ __launch_bounds__(256) void gemm_qkv(const u16* __restrict__ A,
    const u16* __restrict__ wT, const float* __restrict__ bqp,
    const float* __restrict__ bvp, u16* __restrict__ qp, u16* __restrict__ kp,
    u16* __restrict__ vp) {
  int z = blockIdx.z;
  const u16* BT = wT + (size_t)z * (NS*NS);
  const float* bias = (z == 0) ? bqp : ((z == 2) ? bvp : nullptr);
  u16* C = (z == 0) ? qp : ((z == 1) ? kp : vp);
  float scale = (z == 0) ? 0.125f : 1.0f;
  int transOut = (z == 2);

  int m0 = blockIdx.x * 128, n0 = blockIdx.y * 128;
  int tid = threadIdx.x, lane = tid & 63, wid = tid >> 6;
  int l15 = lane & 15, g = lane >> 4;
  int wm = wid >> 1, wn = wid & 1;
  __shared__ u16 sA[2][128*32];
  __shared__ u16 sB[2][128*32];
  f32x4 acc[4][4] = {};

  auto stage = [&](int buf, int kt) {
    int k0 = kt * 32;
    #pragma unroll
    for (int s2 = 0; s2 < 2; s2++) {
      int T = s2*256 + tid;
      gload16(&A [(size_t)(m0 + (T>>2))*NS + k0 + (T&3)*8], &sA[buf][(s2*256 + wid*64)*8]);
    }
    #pragma unroll
    for (int s2 = 0; s2 < 2; s2++) {
      int T = s2*256 + tid;
      gload16(&BT[(size_t)(n0 + (T>>2))*NS + k0 + (T&3)*8], &sB[buf][(s2*256 + wid*64)*8]);
    }
  };
  auto compute = [&](int buf) {
    short8 af[4], bf_[4];
    #pragma unroll
    for (int i = 0; i < 4; i++)
      af[i] = *reinterpret_cast<const short8*>(&sA[buf][(wm*64 + i*16 + l15)*32 + g*8]);
    #pragma unroll
    for (int j = 0; j < 4; j++)
      bf_[j] = *reinterpret_cast<const short8*>(&sB[buf][(wn*64 + j*16 + l15)*32 + g*8]);
    #pragma unroll
    for (int i = 0; i < 4; i++)
      #pragma unroll
      for (int j = 0; j < 4; j++)
        acc[i][j] = MFMA(af[i], bf_[j], acc[i][j]);
  };

  stage(0, 0);
  __syncthreads();
  int cur = 0;
  for (int kt = 0; kt < 31; kt++) {
    stage(cur ^ 1, kt + 1);
    compute(cur);
    __syncthreads();
    cur ^= 1;
  }
  compute(cur);

  if (!transOut) {
    #pragma unroll
    for (int i = 0; i < 4; i++)
      #pragma unroll
      for (int r = 0; r < 4; r++) {
        int row = m0 + wm*64 + i*16 + g*4 + r;
        #pragma unroll
        for (int j = 0; j < 4; j++) {
          int col = n0 + wn*64 + j*16 + l15;
          float v = acc[i][j][r];
          if (bias && row < NCTX) v += bias[col];
          C[(size_t)row*NS + col] = f2bf(v * scale);
        }
      }
  } else {
    #pragma unroll
    for (int i = 0; i < 4; i++)
      #pragma unroll
      for (int j = 0; j < 4; j++) {
        int col  = n0 + wn*64 + j*16 + l15;
        int rowb = m0 + wm*64 + i*16 + g*4;
        u16 ov[4];
        #pragma unroll
        for (int r = 0; r < 4; r++) {
          float v = acc[i][j][r];
          if (bias && (rowb + r) < NCTX) v += bias[col];
          ov[r] = f2bf(v * scale);
        }
        ushort4 o; o.x = ov[0]; o.y = ov[1]; o.z = ov[2]; o.w = ov[3];
        *reinterpret_cast<ushort4*>(&C[(size_t)col*TPAD + rowb]) = o;
      }
  }
}

// ------------------- Flash attention with additive bias ---------------------
// grid (64 q-tiles, 16 heads), 256 thr = 4 waves, QBLK=64 (16 rows/wave), KBLK=64
__global__ __launch_bounds__(256) void attn_kernel(const u16* __restrict__ q,
    const u16* __restrict__ k, const u16* __restrict__ vt,
    const float* __restrict__ bias, u16* __restrict__ ao) {
  int h  = blockIdx.y;
  int q0 = blockIdx.x * 64;
  int tid = threadIdx.x, lane = tid & 63, w = tid >> 6;
  int l15 = lane & 15, g = lane >> 4;
  int qr = q0 + w*16;
  __shared__ u16 pls[4][16][72];   // +8 col pad: 2-way banks on b128 reads

  short8 aq[2];
  aq[0] = *reinterpret_cast<const short8*>(&q[(size_t)(qr + l15)*NS + h*DH + g*8]);
  aq[1] = *reinterpret_cast<const short8*>(&q[(size_t)(qr + l15)*NS + h*DH + 32 + g*8]);

  f32x4 o[4] = {};
  float mrow[4] = {-1e30f, -1e30f, -1e30f, -1e30f};
  float lrow[4] = {};

  for (int kt = 0; kt < 64; kt++) {
    int k0 = kt * 64;
    f32x4 s[4] = {};
    #pragma unroll
    for (int c = 0; c < 4; c++) {
      short8 b0 = *reinterpret_cast<const short8*>(&k[(size_t)(k0 + c*16 + l15)*NS + h*DH + g*8]);
      short8 b1 = *reinterpret_cast<const short8*>(&k[(size_t)(k0 + c*16 + l15)*NS + h*DH + 32 + g*8]);
      s[c] = MFMA(aq[0], b0, s[c]);
      s[c] = MFMA(aq[1], b1, s[c]);
    }
    #pragma unroll
    for (int c = 0; c < 4; c++)
      #pragma unroll
      for (int r = 0; r < 4; r++)
        s[c][r] += bias[(size_t)(qr + g*4 + r)*TPAD + k0 + c*16 + l15];

    float pm[4], mn[4], cs[4], rs[4];
    #pragma unroll
    for (int r = 0; r < 4; r++)
      pm[r] = fmaxf(fmaxf(s[0][r], s[1][r]), fmaxf(s[2][r], s[3][r]));
    #pragma unroll
    for (int off = 1; off < 16; off <<= 1)
      #pragma unroll
      for (int r = 0; r < 4; r++)
        pm[r] = fmaxf(pm[r], __shfl_xor(pm[r], off));
    #pragma unroll
    for (int r = 0; r < 4; r++) {
      mn[r] = fmaxf(mrow[r], pm[r]);
      cs[r] = __expf(mrow[r] - mn[r]);
      mrow[r] = mn[r];
      rs[r] = 0.f;
    }
    #pragma unroll
    for (int c = 0; c < 4; c++)
      #pragma unroll
      for (int r = 0; r < 4; r++) {
        float p = __expf(s[c][r] - mn[r]);
        s[c][r] = p;
        rs[r] += p;
      }
    #pragma unroll
    for (int off = 1; off < 16; off <<= 1)
      #pragma unroll
      for (int r = 0; r < 4; r++)
        rs[r] += __shfl_xor(rs[r], off);
    #pragma unroll
    for (int r = 0; r < 4; r++)
      lrow[r] = lrow[r]*cs[r] + rs[r];
    #pragma unroll
    for (int d = 0; d < 4; d++)
      #pragma unroll
      for (int r = 0; r < 4; r++)
        o[d][r] *= cs[r];

    #pragma unroll
    for (int c = 0; c < 4; c++)
      #pragma unroll
      for (int r = 0; r < 4; r++)
        pls[w][g*4 + r][c*16 + l15] = f2bf(s[c][r]);

    short8 pa0 = *reinterpret_cast<const short8*>(&pls[w][l15][g*8]);
    short8 pa1 = *reinterpret_cast<const short8*>(&pls[w][l15][32 + g*8]);
    #pragma unroll
    for (int d = 0; d < 4; d++) {
      short8 v0 = *reinterpret_cast<const short8*>(&vt[(size_t)(h*DH + d*16 + l15)*TPAD + k0 + g*8]);
      short8 v1 = *reinterpret_cast<const short8*>(&vt[(size_t)(h*DH + d*16 + l15)*TPAD + k0 + 32 + g*8]);
      o[d] = MFMA(pa0, v0, o[d]);
      o[d] = MFMA(pa1, v1, o[d]);
    }
  }
  float inv[4];
  #pragma unroll
  for (int r = 0; r < 4; r++) inv[r] = 1.f / lrow[r];
  #pragma unroll
  for (int d = 0; d < 4; d++)
    #pragma unroll
    for (int r = 0; r < 4; r++)
      ao[(size_t)(qr + g*4 + r)*NS + h*DH + d*16 + l15] = f2bf(o[d][r] * inv[r]);
}

// -------- Final GEMM: out = m + ao @ Wc + bc (fp32 out, rows < 4080) --------
__global__ __launch_bounds__(256) void gemm_final(const u16* __restrict__ A,
    const u16* __restrict__ BT, const float* __restrict__ bc,
    const float* __restrict__ mm, float* __restrict__ out) {
  int m0 = blockIdx.x * 128, n0 = blockIdx.y * 128;
  int tid = threadIdx.x, lane = tid & 63, wid = tid >> 6;
  int l15 = lane & 15, g = lane >> 4;
  int wm = wid >> 1, wn = wid & 1;
  __shared__ u16 sA[2][128*32];
  __shared__ u16 sB[2][128*32];
  f32x4 acc[4][4] = {};

  auto stage = [&](int buf, int kt) {
    int k0 = kt * 32;
    #pragma unroll
    for (int s2 = 0; s2 < 2; s2++) {
      int T = s2*256 + tid;
      gload16(&A [(size_t)(m0 + (T>>2))*NS + k0 + (T&3)*8], &sA[buf][(s2*256 + wid*64)*8]);
    }
    #pragma unroll
    for (int s2 = 0; s2 < 2; s2++) {
      int T = s2*256 + tid;
      gload16(&BT[(size_t)(n0 + (T>>2))*NS + k0 + (T&3)*8], &sB[buf][(s2*256 + wid*64)*8]);
    }
  };
  auto compute = [&](int buf) {
    short8 af[4], bf_[4];
    #pragma unroll
    for (int i = 0; i < 4; i++)
      af[i] = *reinterpret_cast<const short8*>(&sA[buf][(wm*64 + i*16 + l15)*32 + g*8]);
    #pragma unroll
    for (int j = 0; j < 4; j++)
      bf_[j] = *reinterpret_cast<const short8*>(&sB[buf][(wn*64 + j*16 + l15)*32 + g*8]);
    #pragma unroll
    for (int i = 0; i < 4; i++)
      #pragma unroll
      for (int j = 0; j < 4; j++)
        acc[i][j] = MFMA(af[i], bf_[j], acc[i][j]);
  };

  stage(0, 0);
  __syncthreads();
  int cur = 0;
  for (int kt = 0; kt < 31; kt++) {
    stage(cur ^ 1, kt + 1);
    compute(cur);
    __syncthreads();
    cur ^= 1;
  }
  compute(cur);

  #pragma unroll
  for (int i = 0; i < 4; i++)
    #pragma unroll
    for (int r = 0; r < 4; r++) {
      int row = m0 + wm*64 + i*16 + g*4 + r;
      if (row >= NCTX) continue;
      #pragma unroll
      for (int j = 0; j < 4; j++) {
        int col = n0 + wn*64 + j*16 + l15;
        out[(size_t)row*NS + col] = acc[i][j][r] + bc[col] + mm[(size_t)row*NS + col];
      }
    }
}

extern "C" void kernel_launch(void* const* d_in, const int* in_sizes, int n_in,
                              void* d_out, int out_size, void* d_ws, size_t ws_size,
                              hipStream_t stream) {
  (void)in_sizes; (void)n_in; (void)out_size; (void)ws_size;
  const float* mm    = (const float*)d_in[0];
  const float* bias  = (const float*)d_in[1];
  const float* gamma = (const float*)d_in[2];
  const float* beta  = (const float*)d_in[3];
  const float* Wq    = (const float*)d_in[4];
  const float* bq    = (const float*)d_in[5];
  const float* Wk    = (const float*)d_in[6];
  const float* Wv    = (const float*)d_in[7];
  const float* bv    = (const float*)d_in[8];
  const float* Wc    = (const float*)d_in[9];
  const float* bc    = (const float*)d_in[10];

  char* ws = (char*)d_ws;
  const size_t MB = 1u << 20;
  u16* rbf = (u16*)(ws +  0*MB);   // 4096x1024 bf16
  u16* qbf = (u16*)(ws +  8*MB);   // 4096x1024 (pre-scaled by 1/8)
  u16* kbf = (u16*)(ws + 16*MB);   // 4096x1024
  u16* vtb = (u16*)(ws + 24*MB);   // 1024x4096 (V^T)
  u16* wT  = (u16*)(ws + 32*MB);   // 4 x (1024x1024) bf16 W^T: q,k,v,c
  u16* aob = (u16*)(ws + 40*MB);   // 4096x1024 attention out

  ln_kernel   <<<TPAD, 256, 0, stream>>>(mm, gamma, beta, rbf);
  wconv_kernel<<<dim3(16,16,4), 256, 0, stream>>>(Wq, Wk, Wv, Wc, wT);
  gemm_qkv    <<<dim3(32,8,3), 256, 0, stream>>>(rbf, wT, bq, bv, qbf, kbf, vtb);
  attn_kernel <<<dim3(64,16), 256, 0, stream>>>(qbf, kbf, vtb, bias, aob);
  gemm_final  <<<dim3(32,8), 256, 0, stream>>>(aob, wT + 3*(NS*NS), bc, mm, (float*)d_out);
}

// Round 2
// 564.817 us; speedup vs baseline: 1.3049x; 1.3049x over previous
//
#include <hip/hip_runtime.h>
#include <hip/hip_bf16.h>

#define NCTX 4080
#define TPAD 4096
#define NS   1024
#define NH   16
#define DH   64

typedef __attribute__((ext_vector_type(8))) short short8;
typedef __attribute__((ext_vector_type(4))) float f32x4;
typedef unsigned short u16;
typedef unsigned int   u32;

#define MFMA(a,b,c) __builtin_amdgcn_mfma_f32_16x16x32_bf16(a,b,c,0,0,0)

__device__ __forceinline__ u16 f2bf(float f) {
  u32 u = __float_as_uint(f);
  u += 0x7fffu + ((u >> 16) & 1u);   // RNE; inputs are finite
  return (u16)(u >> 16);
}

__device__ __forceinline__ void gload16(const void* g, void* l) {
  __builtin_amdgcn_global_load_lds(
      (const __attribute__((address_space(1))) u32*)g,
      (__attribute__((address_space(3))) u32*)l, 16, 0, 0);
}

// ---------------- LayerNorm -> bf16 r (zero-padded to 4096 rows) -------------
__global__ __launch_bounds__(256) void ln_kernel(const float* __restrict__ mm,
    const float* __restrict__ gamma, const float* __restrict__ beta,
    u16* __restrict__ r) {
  int row = blockIdx.x;
  int t = threadIdx.x;
  if (row >= NCTX) {
    ushort4 z; z.x = z.y = z.z = z.w = 0;
    *reinterpret_cast<ushort4*>(&r[(size_t)row*NS + t*4]) = z;
    return;
  }
  float4 x = *reinterpret_cast<const float4*>(&mm[(size_t)row*NS + t*4]);
  float s  = x.x + x.y + x.z + x.w;
  float ss = x.x*x.x + x.y*x.y + x.z*x.z + x.w*x.w;
  for (int off = 32; off > 0; off >>= 1) {
    s  += __shfl_down(s, off);
    ss += __shfl_down(ss, off);
  }
  __shared__ float red[2][4];
  int wid = t >> 6, lane = t & 63;
  if (lane == 0) { red[0][wid] = s; red[1][wid] = ss; }
  __syncthreads();
  s  = red[0][0] + red[0][1] + red[0][2] + red[0][3];
  ss = red[1][0] + red[1][1] + red[1][2] + red[1][3];
  float mu  = s * (1.f/NS);
  float var = ss * (1.f/NS) - mu*mu;
  float rs  = rsqrtf(var + 1e-5f);
  float4 g = *reinterpret_cast<const float4*>(&gamma[t*4]);
  float4 b = *reinterpret_cast<const float4*>(&beta[t*4]);
  ushort4 o;
  o.x = f2bf((x.x - mu)*rs*g.x + b.x);
  o.y = f2bf((x.y - mu)*rs*g.y + b.y);
  o.z = f2bf((x.z - mu)*rs*g.z + b.z);
  o.w = f2bf((x.w - mu)*rs*g.w + b.w);
  *reinterpret_cast<ushort4*>(&r[(size_t)row*NS + t*4]) = o;
}

// ------------- Weight convert: W (KxN f32) -> W^T (NxK bf16) ----------------
__global__ __launch_bounds__(256) void wconv_kernel(const float* __restrict__ W0,
    const float* __restrict__ W1, const float* __restrict__ W2,
    const float* __restrict__ W3, u16* __restrict__ dstbase) {
  const float* srcs[4] = {W0, W1, W2, W3};
  const float* W = srcs[blockIdx.z];
  u16* dst = dstbase + (size_t)blockIdx.z * NS * NS;
  int k0 = blockIdx.x * 64, n0 = blockIdx.y * 64;
  __shared__ float tile[64][65];
  int t = threadIdx.x;
  int rr = t >> 4;
  int c4 = (t & 15) * 4;
  #pragma unroll
  for (int sb = 0; sb < 4; sb++) {
    int rowk = rr + sb*16;
    float4 v = *reinterpret_cast<const float4*>(&W[(size_t)(k0+rowk)*NS + n0 + c4]);
    tile[rowk][c4] = v.x; tile[rowk][c4+1] = v.y;
    tile[rowk][c4+2] = v.z; tile[rowk][c4+3] = v.w;
  }
  __syncthreads();
  #pragma unroll
  for (int sb = 0; sb < 4; sb++) {
    int nn = rr + sb*16;
    ushort4 o;
    o.x = f2bf(tile[c4  ][nn]);
    o.y = f2bf(tile[c4+1][nn]);
    o.z = f2bf(tile[c4+2][nn]);
    o.w = f2bf(tile[c4+3][nn]);
    *reinterpret_cast<ushort4*>(&dst[(size_t)(n0+nn)*NS + k0 + c4]) = o;
  }
}

// --------- QKV projection GEMM: C = r @ W (+bias) (tile 128x128, BK=32) -----
// z=0: q (scale 1/8, bias bq, row-major)  z=1: k (no bias)  z=2: v (bias bv, transposed out)
__global__ __launch_bounds__(256) void gemm_qkv(const u16* __restrict__ A,
    const u16* __restrict__ wT, const float* __restrict__ bqp,
    const float* __restrict__ bvp, u16* __restrict__ qp, u16* __restrict__ kp,
    u16* __restrict__ vp) {
  int z = blockIdx.z;
  const u16* BT = wT + (size_t)z * (NS*NS);
  const float* bias = (z == 0) ? bqp : ((z == 2) ? bvp : nullptr);
  u16* C = (z == 0) ? qp : ((z == 1) ? kp : vp);
  float scale = (z == 0) ? 0.125f : 1.0f;
  int transOut = (z == 2);

  int m0 = blockIdx.x * 128, n0 = blockIdx.y * 128;
  int tid = threadIdx.x, lane = tid & 63, wid = tid >> 6;
  int l15 = lane & 15, g = lane >> 4;
  int wm = wid >> 1, wn = wid & 1;
  __shared__ u16 sA[2][128*32];
  __shared__ u16 sB[2][128*32];
  f32x4 acc[4][4] = {};

  auto stage = [&](int buf, int kt) {
    int k0 = kt * 32;
    #pragma unroll
    for (int s2 = 0; s2 < 2; s2++) {
      int T = s2*256 + tid;
      gload16(&A [(size_t)(m0 + (T>>2))*NS + k0 + (T&3)*8], &sA[buf][(s2*256 + wid*64)*8]);
    }
    #pragma unroll
    for (int s2 = 0; s2 < 2; s2++) {
      int T = s2*256 + tid;
      gload16(&BT[(size_t)(n0 + (T>>2))*NS + k0 + (T&3)*8], &sB[buf][(s2*256 + wid*64)*8]);
    }
  };
  auto compute = [&](int buf) {
    short8 af[4], bf_[4];
    #pragma unroll
    for (int i = 0; i < 4; i++)
      af[i] = *reinterpret_cast<const short8*>(&sA[buf][(wm*64 + i*16 + l15)*32 + g*8]);
    #pragma unroll
    for (int j = 0; j < 4; j++)
      bf_[j] = *reinterpret_cast<const short8*>(&sB[buf][(wn*64 + j*16 + l15)*32 + g*8]);
    #pragma unroll
    for (int i = 0; i < 4; i++)
      #pragma unroll
      for (int j = 0; j < 4; j++)
        acc[i][j] = MFMA(af[i], bf_[j], acc[i][j]);
  };

  stage(0, 0);
  __syncthreads();
  int cur = 0;
  for (int kt = 0; kt < 31; kt++) {
    stage(cur ^ 1, kt + 1);
    compute(cur);
    __syncthreads();
    cur ^= 1;
  }
  compute(cur);

  if (!transOut) {
    #pragma unroll
    for (int i = 0; i < 4; i++)
      #pragma unroll
      for (int r = 0; r < 4; r++) {
        int row = m0 + wm*64 + i*16 + g*4 + r;
        #pragma unroll
        for (int j = 0; j < 4; j++) {
          int col = n0 + wn*64 + j*16 + l15;
          float v = acc[i][j][r];
          if (bias && row < NCTX) v += bias[col];
          C[(size_t)row*NS + col] = f2bf(v * scale);
        }
      }
  } else {
    #pragma unroll
    for (int i = 0; i < 4; i++)
      #pragma unroll
      for (int j = 0; j < 4; j++) {
        int col  = n0 + wn*64 + j*16 + l15;
        int rowb = m0 + wm*64 + i*16 + g*4;
        u16 ov[4];
        #pragma unroll
        for (int r = 0; r < 4; r++) {
          float v = acc[i][j][r];
          if (bias && (rowb + r) < NCTX) v += bias[col];
          ov[r] = f2bf(v * scale);
        }
        ushort4 o; o.x = ov[0]; o.y = ov[1]; o.z = ov[2]; o.w = ov[3];
        *reinterpret_cast<ushort4*>(&C[(size_t)col*TPAD + rowb]) = o;
      }
  }
}

// ------------------- Flash attention with additive bias ---------------------
// Swapped-orientation (S^T = K x Q^T): lane owns ONE q-row, 4-consecutive-k
// score groups -> float4 bias loads, b64 P-stores, scalar per-lane m/l.
// grid (16 heads, 64 q-tiles), 256 thr = 4 waves, 16 q-rows/wave, KBLK=64.
// K staged in LDS (double-buffered, XOR-swizzled via pre-swizzled source).
__global__ __launch_bounds__(256, 4) void attn_kernel(const u16* __restrict__ q,
    const u16* __restrict__ kp, const u16* __restrict__ vt,
    const float* __restrict__ bias, u16* __restrict__ ao) {
  int h  = blockIdx.x;
  int q0 = blockIdx.y * 64;
  int tid = threadIdx.x, lane = tid & 63, w = tid >> 6;
  int l15 = lane & 15, g = lane >> 4;
  int qr = q0 + w*16;

  __shared__ u16 sK[2][64][64];    // [k-local][d], XOR-swizzled rows
  __shared__ u16 sP[4][16][72];    // per-wave P[q-local][k-local], +8 pad

  auto stageK = [&](int buf, int kt) {
    int k0 = kt * 64;
    #pragma unroll
    for (int s2 = 0; s2 < 2; s2++) {
      int slot = s2*256 + tid;            // 16B slot, 8 per 128B row
      int row  = slot >> 3;
      int kb   = (slot & 7) << 4;
      int kbs  = kb ^ ((row & 7) << 4);   // pre-swizzle SOURCE (m173)
      gload16(&kp[(size_t)(k0 + row)*NS + h*DH + (kbs >> 1)],
              &sK[buf][0][0] + (size_t)(s2*256 + w*64)*8);
    }
  };

  short8 aq[2];
  aq[0] = *reinterpret_cast<const short8*>(&q[(size_t)(qr + l15)*NS + h*DH + g*8]);
  aq[1] = *reinterpret_cast<const short8*>(&q[(size_t)(qr + l15)*NS + h*DH + 32 + g*8]);

  f32x4 o[4] = {};
  float m = -1e30f, l = 0.f;

  stageK(0, 0);
  __syncthreads();

  for (int kt = 0; kt < 64; kt++) {
    int buf = kt & 1;
    if (kt < 63) stageK(buf ^ 1, kt + 1);
    int k0 = kt * 64;

    // bias prefetch: lane's q-row, 4 consecutive k per c-tile
    float4 bb[4];
    #pragma unroll
    for (int c = 0; c < 4; c++)
      bb[c] = *reinterpret_cast<const float4*>(
          &bias[(size_t)(qr + l15)*TPAD + k0 + c*16 + g*4]);

    // QK^T swapped: S^T[k][q] = MFMA(K_frag, Q_frag)
    f32x4 s[4];
    int sw = (l15 & 7) << 4;
    #pragma unroll
    for (int c = 0; c < 4; c++) {
      int rowl = c*16 + l15;
      short8 kf0 = *reinterpret_cast<const short8*>(&sK[buf][rowl][((g*16) ^ sw) >> 1]);
      short8 kf1 = *reinterpret_cast<const short8*>(&sK[buf][rowl][((64 + g*16) ^ sw) >> 1]);
      f32x4 t = {};
      t = MFMA(kf0, aq[0], t);
      t = MFMA(kf1, aq[1], t);
      s[c] = t;
    }

    // V prefetch (global, per-wave) — independent, issue before softmax
    short8 vf[4][2];
    #pragma unroll
    for (int d = 0; d < 4; d++)
      #pragma unroll
      for (int kc = 0; kc < 2; kc++)
        vf[d][kc] = *reinterpret_cast<const short8*>(
            &vt[(size_t)(h*DH + d*16 + l15)*TPAD + k0 + kc*32 + g*8]);

    #pragma unroll
    for (int c = 0; c < 4; c++) {
      s[c][0] += bb[c].x; s[c][1] += bb[c].y;
      s[c][2] += bb[c].z; s[c][3] += bb[c].w;
    }

    // online softmax: lane owns one q-row (16 k-scores this tile)
    float pm = fmaxf(fmaxf(fmaxf(s[0][0], s[0][1]), fmaxf(s[0][2], s[0][3])),
                     fmaxf(fmaxf(s[1][0], s[1][1]), fmaxf(s[1][2], s[1][3])));
    pm = fmaxf(pm, fmaxf(fmaxf(fmaxf(s[2][0], s[2][1]), fmaxf(s[2][2], s[2][3])),
                         fmaxf(fmaxf(s[3][0], s[3][1]), fmaxf(s[3][2], s[3][3]))));
    pm = fmaxf(pm, __shfl_xor(pm, 16));
    pm = fmaxf(pm, __shfl_xor(pm, 32));
    float mn = fmaxf(m, pm);
    float cs = __expf(m - mn);
    m = mn;
    float rs = 0.f;
    #pragma unroll
    for (int c = 0; c < 4; c++)
      #pragma unroll
      for (int r = 0; r < 4; r++) {
        float p = __expf(s[c][r] - mn);
        s[c][r] = p;
        rs += p;
      }
    rs += __shfl_xor(rs, 16);
    rs += __shfl_xor(rs, 32);
    l = l*cs + rs;
    #pragma unroll
    for (int d = 0; d < 4; d++)
      #pragma unroll
      for (int r = 0; r < 4; r++)
        o[d][r] *= cs;

    // P pack (cvt_pk) + b64 stores: lane writes its 4-consecutive-k groups
    #pragma unroll
    for (int c = 0; c < 4; c++) {
      u32 w0, w1;
      asm("v_cvt_pk_bf16_f32 %0, %1, %2" : "=v"(w0) : "v"(s[c][0]), "v"(s[c][1]));
      asm("v_cvt_pk_bf16_f32 %0, %1, %2" : "=v"(w1) : "v"(s[c][2]), "v"(s[c][3]));
      uint2 pw; pw.x = w0; pw.y = w1;
      *reinterpret_cast<uint2*>(&sP[w][l15][c*16 + g*4]) = pw;
    }

    // PV swapped: O^T[d][q] = MFMA(V^T_frag, P_frag)
    short8 pa0 = *reinterpret_cast<const short8*>(&sP[w][l15][g*8]);
    short8 pa1 = *reinterpret_cast<const short8*>(&sP[w][l15][32 + g*8]);
    #pragma unroll
    for (int d = 0; d < 4; d++) {
      o[d] = MFMA(vf[d][0], pa0, o[d]);
      o[d] = MFMA(vf[d][1], pa1, o[d]);
    }
    __syncthreads();
  }

  float inv = 1.f / l;
  #pragma unroll
  for (int d = 0; d < 4; d++) {
    ushort4 ov;
    ov.x = f2bf(o[d][0] * inv);
    ov.y = f2bf(o[d][1] * inv);
    ov.z = f2bf(o[d][2] * inv);
    ov.w = f2bf(o[d][3] * inv);
    *reinterpret_cast<ushort4*>(
        &ao[(size_t)(qr + l15)*NS + h*DH + d*16 + g*4]) = ov;
  }
}

// -------- Final GEMM: out = m + ao @ Wc + bc (fp32 out, rows < 4080) --------
__global__ __launch_bounds__(256) void gemm_final(const u16* __restrict__ A,
    const u16* __restrict__ BT, const float* __restrict__ bc,
    const float* __restrict__ mm, float* __restrict__ out) {
  int m0 = blockIdx.x * 128, n0 = blockIdx.y * 128;
  int tid = threadIdx.x, lane = tid & 63, wid = tid >> 6;
  int l15 = lane & 15, g = lane >> 4;
  int wm = wid >> 1, wn = wid & 1;
  __shared__ u16 sA[2][128*32];
  __shared__ u16 sB[2][128*32];
  f32x4 acc[4][4] = {};

  auto stage = [&](int buf, int kt) {
    int k0 = kt * 32;
    #pragma unroll
    for (int s2 = 0; s2 < 2; s2++) {
      int T = s2*256 + tid;
      gload16(&A [(size_t)(m0 + (T>>2))*NS + k0 + (T&3)*8], &sA[buf][(s2*256 + wid*64)*8]);
    }
    #pragma unroll
    for (int s2 = 0; s2 < 2; s2++) {
      int T = s2*256 + tid;
      gload16(&BT[(size_t)(n0 + (T>>2))*NS + k0 + (T&3)*8], &sB[buf][(s2*256 + wid*64)*8]);
    }
  };
  auto compute = [&](int buf) {
    short8 af[4], bf_[4];
    #pragma unroll
    for (int i = 0; i < 4; i++)
      af[i] = *reinterpret_cast<const short8*>(&sA[buf][(wm*64 + i*16 + l15)*32 + g*8]);
    #pragma unroll
    for (int j = 0; j < 4; j++)
      bf_[j] = *reinterpret_cast<const short8*>(&sB[buf][(wn*64 + j*16 + l15)*32 + g*8]);
    #pragma unroll
    for (int i = 0; i < 4; i++)
      #pragma unroll
      for (int j = 0; j < 4; j++)
        acc[i][j] = MFMA(af[i], bf_[j], acc[i][j]);
  };

  stage(0, 0);
  __syncthreads();
  int cur = 0;
  for (int kt = 0; kt < 31; kt++) {
    stage(cur ^ 1, kt + 1);
    compute(cur);
    __syncthreads();
    cur ^= 1;
  }
  compute(cur);

  #pragma unroll
  for (int i = 0; i < 4; i++)
    #pragma unroll
    for (int r = 0; r < 4; r++) {
      int row = m0 + wm*64 + i*16 + g*4 + r;
      if (row >= NCTX) continue;
      #pragma unroll
      for (int j = 0; j < 4; j++) {
        int col = n0 + wn*64 + j*16 + l15;
        out[(size_t)row*NS + col] = acc[i][j][r] + bc[col] + mm[(size_t)row*NS + col];
      }
    }
}

extern "C" void kernel_launch(void* const* d_in, const int* in_sizes, int n_in,
                              void* d_out, int out_size, void* d_ws, size_t ws_size,
                              hipStream_t stream) {
  (void)in_sizes; (void)n_in; (void)out_size; (void)ws_size;
  const float* mm    = (const float*)d_in[0];
  const float* bias  = (const float*)d_in[1];
  const float* gamma = (const float*)d_in[2];
  const float* beta  = (const float*)d_in[3];
  const float* Wq    = (const float*)d_in[4];
  const float* bq    = (const float*)d_in[5];
  const float* Wk    = (const float*)d_in[6];
  const float* Wv    = (const float*)d_in[7];
  const float* bv    = (const float*)d_in[8];
  const float* Wc    = (const float*)d_in[9];
  const float* bc    = (const float*)d_in[10];

  char* ws = (char*)d_ws;
  const size_t MB = 1u << 20;
  u16* rbf = (u16*)(ws +  0*MB);   // 4096x1024 bf16
  u16* qbf = (u16*)(ws +  8*MB);   // 4096x1024 (pre-scaled by 1/8)
  u16* kbf = (u16*)(ws + 16*MB);   // 4096x1024
  u16* vtb = (u16*)(ws + 24*MB);   // 1024x4096 (V^T)
  u16* wT  = (u16*)(ws + 32*MB);   // 4 x (1024x1024) bf16 W^T: q,k,v,c
  u16* aob = (u16*)(ws + 40*MB);   // 4096x1024 attention out

  ln_kernel   <<<TPAD, 256, 0, stream>>>(mm, gamma, beta, rbf);
  wconv_kernel<<<dim3(16,16,4), 256, 0, stream>>>(Wq, Wk, Wv, Wc, wT);
  gemm_qkv    <<<dim3(32,8,3), 256, 0, stream>>>(rbf, wT, bq, bv, qbf, kbf, vtb);
  attn_kernel <<<dim3(NH,64), 256, 0, stream>>>(qbf, kbf, vtb, bias, aob);
  gemm_final  <<<dim3(32,8), 256, 0, stream>>>(aob, wT + 3*(NS*NS), bc, mm, (float*)d_out);
}